// Round 13
// baseline (128.731 us; speedup 1.0000x reference)
//
#include <hip/hip_runtime.h>
#include <hip/hip_bf16.h>
#include <hip/hip_fp8.h>

// CrossViewContrast: loss = -mean_i( 2*<z1n_i,z2n_i> - log(sum_j exp(2*<z1n_i,z2n_j>) + 1e-8) )
// N=16384, D=128.
// R8/R11/R12 (best): MX-fp8 K=128 MFMA, 3 kernels, lb(256,8), stride-4 LDS
//   placement: sim 46.5us, total 110.45us. Wall obeys sum-law: matrix(14.7)+
//   VALU(23)+LDS(8) == 46: in-order wave streams alternate MFMA/exp, so exp
//   issue gates on matrix-pipe backpressure -> pipes serialize.
// R13: producer/consumer wave specialization (m114: separate wave streams DO
//   overlap pipes). 512-thr blocks: waves 0-3 = MFMA+staging only (no exp);
//   waves 4-7 = exp+rowsum only (no MFMA). Raw accs handed through a
//   barrier-phased double-buffered LDS ring (no fences, no spin).

#define N_ROWS 16384
#define DIM 128
#define JSPLIT 16
#define COLS_PER_BLOCK (N_ROWS / JSPLIT)   // 1024
#define JCHUNK 32
#define NCHUNK (COLS_PER_BLOCK / JCHUNK)   // 32
#define ROWS_PER_BLOCK 128
#define ITILES (N_ROWS / ROWS_PER_BLOCK)   // 128
#define GRID_TOTAL (ITILES * JSPLIT)       // 2048

// exp(2*sim) = 2^(SCALE*sim); SCALE baked into z1q so MFMA acc is already log2-domain.
#define SCALE 2.8853900817779268f  // 2 * log2(e)

typedef __attribute__((ext_vector_type(8))) int   int8v;   // v8i32: 32 fp8 bytes (MFMA A/B frag)
typedef __attribute__((ext_vector_type(4))) int   int4v;   // one 16B LDS granule
typedef __attribute__((ext_vector_type(4))) float floatx4; // MFMA C/D frag

#if __has_builtin(__builtin_amdgcn_exp2f)
#define EXP2(x) __builtin_amdgcn_exp2f(x)
#else
#define EXP2(x) exp2f(x)
#endif

// fmt 0 = OCP e4m3 for both A and B; scales = e8m0 1.0 in all bytes (identity).
__device__ inline floatx4 mfma_fp8_k128(int8v a, int8v b, floatx4 c) {
  return __builtin_amdgcn_mfma_scale_f32_16x16x128_f8f6f4(
      a, b, c, 0, 0, 0, 0x7F7F7F7F, 0, 0x7F7F7F7F);
}

__device__ inline void gload_lds16(const void* gptr, void* lptr) {
  __builtin_amdgcn_global_load_lds(
      (const __attribute__((address_space(1))) void*)gptr,
      (__attribute__((address_space(3))) void*)lptr, 16, 0, 0);
}

__device__ inline short pack_fp8x2(float x, float y) {
#if __has_builtin(__builtin_amdgcn_cvt_pk_fp8_f32)
  int p = __builtin_amdgcn_cvt_pk_fp8_f32(x, y, 0, false);  // bytes 0,1 of result
  return (short)(p & 0xFFFF);
#else
  __hip_fp8_e4m3 a(x), b(y);
  return (short)((unsigned char)a.__x | ((unsigned short)(unsigned char)b.__x << 8));
#endif
}

// ---------------- Kernel 1: row norms + diagonal + fp8 cast + zero init -----
__global__ __launch_bounds__(256) void norm_kernel(
    const float* __restrict__ z1, const float* __restrict__ z2,
    unsigned char* __restrict__ z1q, unsigned char* __restrict__ z2q,
    float* __restrict__ diag, float* __restrict__ denom,
    float* __restrict__ out) {
  int tid = threadIdx.x;
  int wave = tid >> 6, lane = tid & 63;
  int row = blockIdx.x * 4 + wave;   // one wave per row
  const float2* p1 = (const float2*)(z1 + (size_t)row * DIM);
  const float2* p2 = (const float2*)(z2 + (size_t)row * DIM);
  float2 a = p1[lane], b = p2[lane];
  float s11 = a.x * a.x + a.y * a.y;
  float s22 = b.x * b.x + b.y * b.y;
  float s12 = a.x * b.x + a.y * b.y;
#pragma unroll
  for (int m = 32; m >= 1; m >>= 1) {
    s11 += __shfl_xor(s11, m);
    s22 += __shfl_xor(s22, m);
    s12 += __shfl_xor(s12, m);
  }
  float inv1 = 1.0f / fmaxf(sqrtf(s11), 1e-12f);  // torch F.normalize eps
  float inv2 = 1.0f / fmaxf(sqrtf(s22), 1e-12f);
  float sc1 = inv1 * SCALE;                        // bake exp scale into A side
  // fp8 e4m3 (OCP on gfx950): |z1q| <= SCALE ~ 2.89 << 448 max. k order: 2*lane, 2*lane+1.
  ((short*)(z1q + (size_t)row * DIM))[lane] = pack_fp8x2(a.x * sc1, a.y * sc1);
  ((short*)(z2q + (size_t)row * DIM))[lane] = pack_fp8x2(b.x * inv2, b.y * inv2);
  if (lane == 0) {
    diag[row]  = s12 * inv1 * inv2;  // exact fp32 diagonal
    denom[row] = 0.0f;
  }
  if (blockIdx.x == 0 && tid == 0) out[0] = 0.0f;
}

// ---------------- Kernel 2: denom_i += sum_j exp(2*sim_ij), MX-fp8 MFMA -----
// 512 threads: producer waves 0-3 (MFMA + staging), consumer waves 4-7 (exp+sum).
// B staging: stride-4 granule placement (R10-verified conflict-free). Acc ring:
// accbuf[2][pw][tile][lane], lane-linear 16B writes/reads. One barrier/chunk:
// producers fill accbuf[c&1] while consumers drain accbuf[(c-1)&1].
__global__ __launch_bounds__(512, 4) void sim_kernel(
    const unsigned char* __restrict__ z1q,
    const unsigned char* __restrict__ z2q,
    float* __restrict__ denom) {
  __shared__ int4v   ldsB[2][JCHUNK * 8];    // 2 x 4 KB
  __shared__ floatx4 accbuf[2][4][4][64];    // 2 x 16 KB raw acc tiles

  int tid  = threadIdx.x;
  int wv   = tid >> 6;          // 0..7
  int w    = wv & 3;            // producer/consumer pair index
  int prod = (wv < 4);
  int lane = tid & 63;
  int q    = (lane >> 4) & 3;
  int l15  = lane & 15;
  int s    = l15 & 7;
  int itile  = blockIdx.x & (ITILES - 1);
  int jsplit = blockIdx.x >> 7;
  int i0 = itile * ROWS_PER_BLOCK + w * 32;

  const floatx4 ZERO4 = {0.f, 0.f, 0.f, 0.f};

  const char* Bbase = (const char*)z2q + (size_t)jsplit * COLS_PER_BLOCK * DIM;

  // stage one 4 KB chunk with the first 256 threads (producers): lane-linear
  // LDS dest; physical slot gl of row holds logical o = inv_perm(gl^(row&7)),
  // perm(o)=(o>>1)|((o&1)<<2) -> read offsets q^s (lo) and (q^s)^4 (hi).
#define STAGE(cidx, bufi)                                                    \
  do {                                                                       \
    const char* _ck = Bbase + (size_t)(cidx) * JCHUNK * DIM;                 \
    char* _dst = (char*)&ldsB[bufi][0];                                      \
    int _row = tid >> 3, _gl = tid & 7;                                      \
    int _u = _gl ^ (_row & 7);                                               \
    int _o = 2 * (_u & 3) + (_u >> 2);                                       \
    gload_lds16(_ck + (size_t)_row * DIM + _o * 16,                          \
                _dst + (size_t)tid * 16);                                    \
  } while (0)

  int8v afrag[2];
  if (prod) {
    // A fragments: lane (q,l15) holds bytes [q*32,+32) of row (i0+ii*16+l15).
#pragma unroll
    for (int ii = 0; ii < 2; ++ii) {
      const int4v* rp = (const int4v*)(z1q + (size_t)(i0 + ii * 16 + l15) * DIM);
      int4v* ah = (int4v*)&afrag[ii];
      ah[0] = rp[q * 2];
      ah[1] = rp[q * 2 + 1];
    }
    STAGE(0, 0);
  }
  __syncthreads();

  int lo_v = l15 * 8 + (q ^ s);
  int hi_v = l15 * 8 + ((q ^ s) ^ 4);

  floatx4 rowsum[2];
  rowsum[0] = ZERO4;
  rowsum[1] = ZERO4;

  for (int c = 0; c < NCHUNK; ++c) {
    if (prod) {
      if (c + 1 < NCHUNK) STAGE(c + 1, (c + 1) & 1);
      const int4v* buf = &ldsB[c & 1][0];
      floatx4 acc[4];  // tile t = jj*2 + ii
#pragma unroll
      for (int jj = 0; jj < 2; ++jj) {
        int8v bf;
        int4v* h = (int4v*)&bf;
        h[0] = buf[jj * 128 + lo_v];
        h[1] = buf[jj * 128 + hi_v];
        acc[jj * 2 + 0] = mfma_fp8_k128(afrag[0], bf, ZERO4);
        acc[jj * 2 + 1] = mfma_fp8_k128(afrag[1], bf, ZERO4);
      }
#pragma unroll
      for (int t = 0; t < 4; ++t) accbuf[c & 1][w][t][lane] = acc[t];
    } else if (c > 0) {
      // consume previous chunk's raw accs: exp2 + accumulate
#pragma unroll
      for (int t = 0; t < 4; ++t) {
        floatx4 a = accbuf[(c - 1) & 1][w][t][lane];
        floatx4 e;
#pragma unroll
        for (int r = 0; r < 4; ++r) e[r] = EXP2(a[r]);
        rowsum[t & 1] += e;   // ii = t&1
      }
    }
    __syncthreads();  // hands accbuf[c&1] to consumers; guards B buf reuse
  }

  if (!prod) {
    // drain the final chunk (NCHUNK-1) from buffer (NCHUNK-1)&1
#pragma unroll
    for (int t = 0; t < 4; ++t) {
      floatx4 a = accbuf[(NCHUNK - 1) & 1][w][t][lane];
      floatx4 e;
#pragma unroll
      for (int r = 0; r < 4; ++r) e[r] = EXP2(a[r]);
      rowsum[t & 1] += e;
    }
    // reduce the 16 column-partials (spread over l15) and commit.
    // C/D layout (shape-determined): col = lane&15 (j), row = q*4 + r (i).
#pragma unroll
    for (int ii = 0; ii < 2; ++ii)
#pragma unroll
      for (int r = 0; r < 4; ++r) {
        float v = rowsum[ii][r];
        v += __shfl_xor(v, 1);
        v += __shfl_xor(v, 2);
        v += __shfl_xor(v, 4);
        v += __shfl_xor(v, 8);
        if (l15 == 0) atomicAdd(&denom[i0 + ii * 16 + q * 4 + r], v);
      }
  }
}

// ---------------- Kernel 3: loss = -mean(2*diag - log(denom+eps)) -----------
// 64 blocks x 256 threads; one row/thread; wave-reduce then one atomicAdd/wave.
__global__ __launch_bounds__(256) void loss_kernel(
    const float* __restrict__ denom, const float* __restrict__ diag,
    float* __restrict__ out) {
  int row = blockIdx.x * 256 + threadIdx.x;
  float t = 2.0f * diag[row] - __logf(denom[row] + 1e-8f);
#pragma unroll
  for (int m = 32; m >= 1; m >>= 1) t += __shfl_xor(t, m);
  if ((threadIdx.x & 63) == 0) atomicAdd(out, -t * (1.0f / N_ROWS));
}

extern "C" void kernel_launch(void* const* d_in, const int* in_sizes, int n_in,
                              void* d_out, int out_size, void* d_ws, size_t ws_size,
                              hipStream_t stream) {
  const float* z1 = (const float*)d_in[0];
  const float* z2 = (const float*)d_in[1];
  char* ws = (char*)d_ws;
  unsigned char* z1q = (unsigned char*)ws;                                  // 2 MB
  unsigned char* z2q = (unsigned char*)(ws + (size_t)N_ROWS * DIM);         // 2 MB
  float* denom = (float*)(ws + (size_t)2 * N_ROWS * DIM);                   // 64 KB
  float* diag  = (float*)(ws + (size_t)2 * N_ROWS * DIM + (size_t)N_ROWS * 4);
  float* outp  = (float*)d_out;

  norm_kernel<<<N_ROWS / 4, 256, 0, stream>>>(z1, z2, z1q, z2q, diag, denom, outp);
  sim_kernel<<<GRID_TOTAL, 512, 0, stream>>>(z1q, z2q, denom);
  loss_kernel<<<N_ROWS / 256, 256, 0, stream>>>(denom, diag, outp);
}

// Round 14
// 110.579 us; speedup vs baseline: 1.1642x; 1.1642x over previous
//
#include <hip/hip_runtime.h>
#include <hip/hip_bf16.h>
#include <hip/hip_fp8.h>

// CrossViewContrast: loss = -mean_i( 2*<z1n_i,z2n_i> - log(sum_j exp(2*<z1n_i,z2n_j>) + 1e-8) )
// N=16384, D=128.
// FINAL STATE (= R12, best: 110.45us total, sim 46.5us).
// Ladder: R1 bf16 MFMA 96us -> R2 exp2+log2-bake 76us -> R8 MX-fp8 K=128 47.7us
//   -> R11/R12 stride-4 LDS placement (conflicts 4.19M->0) 46.5us.
// Dead ends (all counter-diagnosed): R3 dbuf prefetch, R4 occupancy 2x, R6 ILP
//   exp-shadow, R12 copy-elision, R13 producer/consumer waves -- sim wall obeys
//   busy-sum law (VALU 23us + matrix 14.7us + LDS ~8us ~= 46.5us); VALU is ~90%
//   fundamental (268M v_exp_f32 @ trans quarter-rate + pk_adds), matrix is AT the
//   4686 TF fp8 ubench floor. R9/R10 loss-fold via device fences: 40-140us TCC
//   stall, abandoned; coop grid-sync launch fails on this harness (R5).
// Remaining 64us is harness launch/reset envelope (invariant across 2 vs 3
//   kernels +-6us; not kernel-addressable).

#define N_ROWS 16384
#define DIM 128
#define JSPLIT 16
#define COLS_PER_BLOCK (N_ROWS / JSPLIT)   // 1024
#define JCHUNK 32
#define NCHUNK (COLS_PER_BLOCK / JCHUNK)   // 32
#define ROWS_PER_BLOCK 128
#define ITILES (N_ROWS / ROWS_PER_BLOCK)   // 128
#define GRID_TOTAL (ITILES * JSPLIT)       // 2048

// exp(2*sim) = 2^(SCALE*sim); SCALE baked into z1q so MFMA acc is already log2-domain.
#define SCALE 2.8853900817779268f  // 2 * log2(e)

typedef __attribute__((ext_vector_type(8))) int   int8v;   // v8i32: 32 fp8 bytes (MFMA A/B frag)
typedef __attribute__((ext_vector_type(4))) int   int4v;   // one 16B LDS granule
typedef __attribute__((ext_vector_type(4))) float floatx4; // MFMA C/D frag

#if __has_builtin(__builtin_amdgcn_exp2f)
#define EXP2(x) __builtin_amdgcn_exp2f(x)
#else
#define EXP2(x) exp2f(x)
#endif

// fmt 0 = OCP e4m3 for both A and B; scales = e8m0 1.0 in all bytes (identity).
__device__ inline floatx4 mfma_fp8_k128(int8v a, int8v b, floatx4 c) {
  return __builtin_amdgcn_mfma_scale_f32_16x16x128_f8f6f4(
      a, b, c, 0, 0, 0, 0x7F7F7F7F, 0, 0x7F7F7F7F);
}

__device__ inline void gload_lds16(const void* gptr, void* lptr) {
  __builtin_amdgcn_global_load_lds(
      (const __attribute__((address_space(1))) void*)gptr,
      (__attribute__((address_space(3))) void*)lptr, 16, 0, 0);
}

__device__ inline short pack_fp8x2(float x, float y) {
#if __has_builtin(__builtin_amdgcn_cvt_pk_fp8_f32)
  int p = __builtin_amdgcn_cvt_pk_fp8_f32(x, y, 0, false);  // bytes 0,1 of result
  return (short)(p & 0xFFFF);
#else
  __hip_fp8_e4m3 a(x), b(y);
  return (short)((unsigned char)a.__x | ((unsigned short)(unsigned char)b.__x << 8));
#endif
}

// ---------------- Kernel 1: row norms + diagonal + fp8 cast + zero init -----
__global__ __launch_bounds__(256) void norm_kernel(
    const float* __restrict__ z1, const float* __restrict__ z2,
    unsigned char* __restrict__ z1q, unsigned char* __restrict__ z2q,
    float* __restrict__ diag, float* __restrict__ denom,
    float* __restrict__ out) {
  int tid = threadIdx.x;
  int wave = tid >> 6, lane = tid & 63;
  int row = blockIdx.x * 4 + wave;   // one wave per row
  const float2* p1 = (const float2*)(z1 + (size_t)row * DIM);
  const float2* p2 = (const float2*)(z2 + (size_t)row * DIM);
  float2 a = p1[lane], b = p2[lane];
  float s11 = a.x * a.x + a.y * a.y;
  float s22 = b.x * b.x + b.y * b.y;
  float s12 = a.x * b.x + a.y * b.y;
#pragma unroll
  for (int m = 32; m >= 1; m >>= 1) {
    s11 += __shfl_xor(s11, m);
    s22 += __shfl_xor(s22, m);
    s12 += __shfl_xor(s12, m);
  }
  float inv1 = 1.0f / fmaxf(sqrtf(s11), 1e-12f);  // torch F.normalize eps
  float inv2 = 1.0f / fmaxf(sqrtf(s22), 1e-12f);
  float sc1 = inv1 * SCALE;                        // bake exp scale into A side
  // fp8 e4m3 (OCP on gfx950): |z1q| <= SCALE ~ 2.89 << 448 max. k order: 2*lane, 2*lane+1.
  ((short*)(z1q + (size_t)row * DIM))[lane] = pack_fp8x2(a.x * sc1, a.y * sc1);
  ((short*)(z2q + (size_t)row * DIM))[lane] = pack_fp8x2(b.x * inv2, b.y * inv2);
  if (lane == 0) {
    diag[row]  = s12 * inv1 * inv2;  // exact fp32 diagonal
    denom[row] = 0.0f;
  }
  if (blockIdx.x == 0 && tid == 0) out[0] = 0.0f;
}

// ---------------- Kernel 2: denom_i += sum_j exp(2*sim_ij), MX-fp8 MFMA -----
// Stride-4 granule placement (R10-verified conflict-free): logical granule o of
// row r stored at physical perm(o)^(r&7), perm(o)=(o>>1)|((o&1)<<2); lane reads
// lo at q^s, hi at (q^s)^4. One K=128 MFMA per 16x16 tile; exp2-flush of the
// other ping-pong accumulator in each MFMA's shadow.
__global__ __launch_bounds__(256, 8) void sim_kernel(
    const unsigned char* __restrict__ z1q,
    const unsigned char* __restrict__ z2q,
    float* __restrict__ denom) {
  __shared__ int4v lds[2][JCHUNK * 8];  // 2 x 4 KB

  int tid = threadIdx.x;
  int w   = tid >> 6;
  int q   = (tid >> 4) & 3;   // quad within wave
  int l15 = tid & 15;
  int s   = l15 & 7;          // swizzle key
  int itile  = blockIdx.x & (ITILES - 1);
  int jsplit = blockIdx.x >> 7;
  int i0 = itile * ROWS_PER_BLOCK + w * 32;

  const floatx4 ZERO4 = {0.f, 0.f, 0.f, 0.f};
  const floatx4 NEG4  = {-1e30f, -1e30f, -1e30f, -1e30f};

  // A fragments: lane (q,l15) holds bytes [q*32, q*32+32) of row (i0+ii*16+l15).
  int8v afrag[2];
#pragma unroll
  for (int ii = 0; ii < 2; ++ii) {
    const int4v* rp = (const int4v*)(z1q + (size_t)(i0 + ii * 16 + l15) * DIM);
    int8v af;
    int4v* ah = (int4v*)&af;
    ah[0] = rp[q * 2];
    ah[1] = rp[q * 2 + 1];
    afrag[ii] = af;
  }

  floatx4 rowsum[2];
  rowsum[0] = ZERO4;
  rowsum[1] = ZERO4;
  // ping-pong accumulators: accA <- ii=0 tiles (flushed to rowsum[0]),
  // accB <- ii=1 tiles (rowsum[1]). Seed -1e30: first flushes add exp2(-1e30)=0.
  floatx4 accA = NEG4, accB = NEG4;

  const char* Bbase = (const char*)z2q + (size_t)jsplit * COLS_PER_BLOCK * DIM;

  // stage one 4 KB chunk: 256 thr x 16 B, lane-linear LDS dest (constraint).
  // physical slot gl of row holds logical o = inv_perm(gl ^ (row&7)):
  //   u = gl ^ (row&7); o = 2*(u&3) + (u>>2)
#define STAGE(cidx, bufi)                                                    \
  do {                                                                       \
    const char* _ck = Bbase + (size_t)(cidx) * JCHUNK * DIM;                 \
    char* _dst = (char*)&lds[bufi][0];                                       \
    int _row = tid >> 3, _gl = tid & 7;                                      \
    int _u = _gl ^ (_row & 7);                                               \
    int _o = 2 * (_u & 3) + (_u >> 2);                                       \
    gload_lds16(_ck + (size_t)_row * DIM + _o * 16,                          \
                _dst + (size_t)tid * 16);                                    \
  } while (0)

  STAGE(0, 0);
  __syncthreads();

  // precomputed lane offsets (int4v units) within a buffer; jj adds a
  // compile-time 128 that folds into the ds_read immediate offset.
  int lo_v = l15 * 8 + (q ^ s);
  int hi_v = l15 * 8 + ((q ^ s) ^ 4);

  for (int c = 0; c < NCHUNK; ++c) {
    if (c + 1 < NCHUNK) STAGE(c + 1, (c + 1) & 1);
    const int4v* buf = &lds[c & 1][0];

#pragma unroll
    for (int jj = 0; jj < 2; ++jj) {
      // B fragment: ds_reads land directly in the int8v register pair.
      int8v bf;
      int4v* h = (int4v*)&bf;
      h[0] = buf[jj * 128 + lo_v];
      h[1] = buf[jj * 128 + hi_v];

      // ii=0: MFMA writes accA in place; flush accB (prev ii=1 tile) in shadow.
      accA = mfma_fp8_k128(afrag[0], bf, ZERO4);
      {
        floatx4 e;
#pragma unroll
        for (int r = 0; r < 4; ++r) e[r] = EXP2(accB[r]);
        rowsum[1] += e;
      }
      // ii=1: MFMA writes accB in place; flush accA (one MFMA ago) in shadow.
      accB = mfma_fp8_k128(afrag[1], bf, ZERO4);
      {
        floatx4 e;
#pragma unroll
        for (int r = 0; r < 4; ++r) e[r] = EXP2(accA[r]);
        rowsum[0] += e;
      }
    }
    __syncthreads();  // guards buf reuse
  }
  // final flush: accB (last ii=1 tile) is still pending.
  {
    floatx4 e;
#pragma unroll
    for (int r = 0; r < 4; ++r) e[r] = EXP2(accB[r]);
    rowsum[1] += e;
  }

  // reduce the 16 column-partials (spread over l15) and commit.
  // C/D layout (shape-determined): col = lane&15 (j), row = q*4 + r (i).
#pragma unroll
  for (int ii = 0; ii < 2; ++ii)
#pragma unroll
    for (int r = 0; r < 4; ++r) {
      float v = rowsum[ii][r];
      v += __shfl_xor(v, 1);
      v += __shfl_xor(v, 2);
      v += __shfl_xor(v, 4);
      v += __shfl_xor(v, 8);
      if (l15 == 0) atomicAdd(&denom[i0 + ii * 16 + q * 4 + r], v);
    }
}

// ---------------- Kernel 3: loss = -mean(2*diag - log(denom+eps)) -----------
// 64 blocks x 256 threads; one row/thread; wave-reduce then one atomicAdd/wave.
__global__ __launch_bounds__(256) void loss_kernel(
    const float* __restrict__ denom, const float* __restrict__ diag,
    float* __restrict__ out) {
  int row = blockIdx.x * 256 + threadIdx.x;
  float t = 2.0f * diag[row] - __logf(denom[row] + 1e-8f);
#pragma unroll
  for (int m = 32; m >= 1; m >>= 1) t += __shfl_xor(t, m);
  if ((threadIdx.x & 63) == 0) atomicAdd(out, -t * (1.0f / N_ROWS));
}

extern "C" void kernel_launch(void* const* d_in, const int* in_sizes, int n_in,
                              void* d_out, int out_size, void* d_ws, size_t ws_size,
                              hipStream_t stream) {
  const float* z1 = (const float*)d_in[0];
  const float* z2 = (const float*)d_in[1];
  char* ws = (char*)d_ws;
  unsigned char* z1q = (unsigned char*)ws;                                  // 2 MB
  unsigned char* z2q = (unsigned char*)(ws + (size_t)N_ROWS * DIM);         // 2 MB
  float* denom = (float*)(ws + (size_t)2 * N_ROWS * DIM);                   // 64 KB
  float* diag  = (float*)(ws + (size_t)2 * N_ROWS * DIM + (size_t)N_ROWS * 4);
  float* outp  = (float*)d_out;

  norm_kernel<<<N_ROWS / 4, 256, 0, stream>>>(z1, z2, z1q, z2q, diag, denom, outp);
  sim_kernel<<<GRID_TOTAL, 256, 0, stream>>>(z1q, z2q, denom);
  loss_kernel<<<N_ROWS / 256, 256, 0, stream>>>(denom, diag, outp);
}